// Round 1
// baseline (525.635 us; speedup 1.0000x reference)
//
#include <hip/hip_runtime.h>
#include <math.h>

// Batched Kalman filter step: B=131072 batches, STATE=16, OBS=8, fp32.
// Layout: 16 threads per batch (thread t owns state-row t), 8 batches per
// 128-thread block. All matmuls are "own row in registers x broadcast LDS
// rows" (broadcast reads are conflict-free). 8x8 SPD solve = redundant
// per-thread register Cholesky (no barriers, no divergence).

#define NB 131072
#define NSTATE 16
#define NOBS 8
#define BATCH_PER_BLOCK 8
#define THREADS (BATCH_PER_BLOCK * 16)

// Per-batch LDS layout (dwords), total 1000 (== 8 mod 32 so the 4 batch
// groups of a wave broadcast from disjoint banks):
//  covA  @   0 : 16x16 stride 16 (cov, later new_cov)
//  Hb    @ 256 : 8x16  stride 17
//  Rb    @ 392 : 8x8   stride 9
//  PHtb  @ 464 : 16x8  stride 9  (later K^T, 8x16 stride 16)
//  Sb    @ 608 : 8x8   stride 9
//  p1T   @ 680 : 16x16 stride 16 (later F^T)
//  meanv @ 936 (16), nmeanv @ 952 (16), residv @ 968 (8), pad -> 1000
#define LDS_PER 1000

__global__ void __launch_bounds__(THREADS)
kalman_step_kernel(const float* __restrict__ input, const float* __restrict__ mean,
                   const float* __restrict__ cov, const float* __restrict__ H,
                   const float* __restrict__ R, const float* __restrict__ F,
                   const float* __restrict__ Q,
                   float* __restrict__ out_mean, float* __restrict__ out_cov)
{
    __shared__ __align__(16) float lds[BATCH_PER_BLOCK * LDS_PER];

    const int tid = threadIdx.x;
    const int g = tid >> 4;        // batch slot in block
    const int t = tid & 15;        // state row
    const long b = (long)blockIdx.x * BATCH_PER_BLOCK + g;

    float* Lb    = lds + g * LDS_PER;
    float* covA  = Lb;
    float* Hb    = Lb + 256;
    float* Rb    = Lb + 392;
    float* PHtb  = Lb + 464;   // later K^T (stride 16)
    float* Sb    = Lb + 608;
    float* p1T   = Lb + 680;   // later F^T
    float* meanv = Lb + 936;
    float* nmeanv= Lb + 952;
    float* residv= Lb + 968;

    // ---------------- Phase 1: global loads ----------------
    // F row t -> regs early (needed late; hide latency)
    float freg[16];
    {
        const float4* F4 = (const float4*)(F + b * 256 + t * 16);
        float4 f0 = F4[0], f1 = F4[1], f2 = F4[2], f3 = F4[3];
        freg[0]=f0.x; freg[1]=f0.y; freg[2]=f0.z; freg[3]=f0.w;
        freg[4]=f1.x; freg[5]=f1.y; freg[6]=f1.z; freg[7]=f1.w;
        freg[8]=f2.x; freg[9]=f2.y; freg[10]=f2.z; freg[11]=f2.w;
        freg[12]=f3.x; freg[13]=f3.y; freg[14]=f3.z; freg[15]=f3.w;
    }
    float covrow[16];
    {
        const float4* C4 = (const float4*)(cov + b * 256 + t * 16);
        float4 c0 = C4[0], c1 = C4[1], c2 = C4[2], c3 = C4[3];
        covrow[0]=c0.x; covrow[1]=c0.y; covrow[2]=c0.z; covrow[3]=c0.w;
        covrow[4]=c1.x; covrow[5]=c1.y; covrow[6]=c1.z; covrow[7]=c1.w;
        covrow[8]=c2.x; covrow[9]=c2.y; covrow[10]=c2.z; covrow[11]=c2.w;
        covrow[12]=c3.x; covrow[13]=c3.y; covrow[14]=c3.z; covrow[15]=c3.w;
        float4* cd = (float4*)(covA + t * 16);
        cd[0]=c0; cd[1]=c1; cd[2]=c2; cd[3]=c3;
    }
    const float m = mean[b * 16 + t];
    meanv[t] = m;
    float inp = 0.0f;
    if (t < NOBS) {
        inp = input[b * 8 + t];
        const float4* H4 = (const float4*)(H + b * 128 + t * 16);
        float4 h0 = H4[0], h1 = H4[1], h2 = H4[2], h3 = H4[3];
        float* hd = Hb + t * 17;
        hd[0]=h0.x; hd[1]=h0.y; hd[2]=h0.z; hd[3]=h0.w;
        hd[4]=h1.x; hd[5]=h1.y; hd[6]=h1.z; hd[7]=h1.w;
        hd[8]=h2.x; hd[9]=h2.y; hd[10]=h2.z; hd[11]=h2.w;
        hd[12]=h3.x; hd[13]=h3.y; hd[14]=h3.z; hd[15]=h3.w;
        const float4* R4 = (const float4*)(R + b * 64 + t * 8);
        float4 r0 = R4[0], r1 = R4[1];
        float* rd = Rb + t * 9;
        rd[0]=r0.x; rd[1]=r0.y; rd[2]=r0.z; rd[3]=r0.w;
        rd[4]=r1.x; rd[5]=r1.y; rd[6]=r1.z; rd[7]=r1.w;
    }
    __syncthreads();

    // ---------------- Phase 2: PHt = cov @ H^T ; resid ----------------
    float pht[8];
    #pragma unroll
    for (int o = 0; o < 8; ++o) {
        float acc = 0.0f;
        #pragma unroll
        for (int j = 0; j < 16; ++j) acc += covrow[j] * Hb[o * 17 + j];
        pht[o] = acc;
        PHtb[t * 9 + o] = acc;
    }
    if (t < NOBS) {
        float acc = inp;
        #pragma unroll
        for (int s = 0; s < 16; ++s) acc -= Hb[t * 17 + s] * meanv[s];
        residv[t] = acc;
    }
    __syncthreads();

    // ---------------- Phase 3: S = H @ PHt + R (rows by t<8) ----------------
    if (t < NOBS) {
        float sreg[8];
        #pragma unroll
        for (int c = 0; c < 8; ++c) sreg[c] = Rb[t * 9 + c];
        #pragma unroll
        for (int s = 0; s < 16; ++s) {
            float h = Hb[t * 17 + s];
            #pragma unroll
            for (int c = 0; c < 8; ++c) sreg[c] += h * PHtb[s * 9 + c];
        }
        #pragma unroll
        for (int c = 0; c < 8; ++c) Sb[t * 9 + c] = sreg[c];
    }
    __syncthreads();

    // ---------------- Phase 4: redundant Cholesky; K row; new_mean ----------------
    float Lm[8][8];
    #pragma unroll
    for (int i = 0; i < 8; ++i)
        #pragma unroll
        for (int j = 0; j <= i; ++j)
            Lm[i][j] = Sb[i * 9 + j];
    float dinv[8];
    #pragma unroll
    for (int k = 0; k < 8; ++k) {
        float diag = Lm[k][k];
        #pragma unroll
        for (int j = 0; j < k; ++j) diag -= Lm[k][j] * Lm[k][j];
        float lkk = sqrtf(diag);
        float inv = 1.0f / lkk;
        dinv[k] = inv;
        #pragma unroll
        for (int i = k + 1; i < 8; ++i) {
            float v = Lm[i][k];
            #pragma unroll
            for (int j = 0; j < k; ++j) v -= Lm[i][j] * Lm[k][j];
            Lm[i][k] = v * inv;
        }
    }
    // Solve S x = pht  (x = K row t): L y = b, L^T x = y
    float yv[8];
    #pragma unroll
    for (int i = 0; i < 8; ++i) {
        float v = pht[i];
        #pragma unroll
        for (int j = 0; j < i; ++j) v -= Lm[i][j] * yv[j];
        yv[i] = v * dinv[i];
    }
    float Kr[8];
    #pragma unroll
    for (int i = 7; i >= 0; --i) {
        float v = yv[i];
        #pragma unroll
        for (int j = i + 1; j < 8; ++j) v -= Lm[j][i] * Kr[j];
        Kr[i] = v * dinv[i];
    }
    // new_mean
    {
        float nm = m;
        #pragma unroll
        for (int o = 0; o < 8; ++o) nm += Kr[o] * residv[o];
        nmeanv[t] = nm;
    }
    // K^T over PHtb region (stride 16); PHtb dead after phase 3
    #pragma unroll
    for (int o = 0; o < 8; ++o) PHtb[o * 16 + t] = Kr[o];
    __syncthreads();

    // ---------------- Phase 5: p1 = I - K@H (row); KR = K@R (row) ----------------
    float p1[16];
    #pragma unroll
    for (int j = 0; j < 16; ++j) p1[j] = (j == t) ? 1.0f : 0.0f;
    #pragma unroll
    for (int o = 0; o < 8; ++o) {
        float ko = Kr[o];
        #pragma unroll
        for (int j = 0; j < 16; ++j) p1[j] -= ko * Hb[o * 17 + j];
    }
    #pragma unroll
    for (int j = 0; j < 16; ++j) p1T[j * 16 + t] = p1[j];
    float KRr[8];
    #pragma unroll
    for (int c = 0; c < 8; ++c) KRr[c] = 0.0f;
    #pragma unroll
    for (int o = 0; o < 8; ++o) {
        float ko = Kr[o];
        #pragma unroll
        for (int c = 0; c < 8; ++c) KRr[c] += ko * Rb[o * 9 + c];
    }
    __syncthreads();

    // ---------------- Phase 6: tmp = p1 @ cov (row) ----------------
    float tmp[16];
    #pragma unroll
    for (int k = 0; k < 16; ++k) tmp[k] = 0.0f;
    #pragma unroll
    for (int j = 0; j < 16; ++j) {
        float pj = p1[j];
        const float4* cr = (const float4*)(covA + j * 16);
        float4 c0 = cr[0], c1 = cr[1], c2 = cr[2], c3 = cr[3];
        tmp[0]+=pj*c0.x; tmp[1]+=pj*c0.y; tmp[2]+=pj*c0.z; tmp[3]+=pj*c0.w;
        tmp[4]+=pj*c1.x; tmp[5]+=pj*c1.y; tmp[6]+=pj*c1.z; tmp[7]+=pj*c1.w;
        tmp[8]+=pj*c2.x; tmp[9]+=pj*c2.y; tmp[10]+=pj*c2.z; tmp[11]+=pj*c2.w;
        tmp[12]+=pj*c3.x; tmp[13]+=pj*c3.y; tmp[14]+=pj*c3.z; tmp[15]+=pj*c3.w;
    }

    // ---------------- Phase 7: new_cov row = tmp @ p1^T + KR @ K^T ----------------
    float nc[16];
    #pragma unroll
    for (int j = 0; j < 16; ++j) nc[j] = 0.0f;
    #pragma unroll
    for (int k = 0; k < 16; ++k) {
        float tk = tmp[k];
        const float4* pr = (const float4*)(p1T + k * 16);
        float4 c0 = pr[0], c1 = pr[1], c2 = pr[2], c3 = pr[3];
        nc[0]+=tk*c0.x; nc[1]+=tk*c0.y; nc[2]+=tk*c0.z; nc[3]+=tk*c0.w;
        nc[4]+=tk*c1.x; nc[5]+=tk*c1.y; nc[6]+=tk*c1.z; nc[7]+=tk*c1.w;
        nc[8]+=tk*c2.x; nc[9]+=tk*c2.y; nc[10]+=tk*c2.z; nc[11]+=tk*c2.w;
        nc[12]+=tk*c3.x; nc[13]+=tk*c3.y; nc[14]+=tk*c3.z; nc[15]+=tk*c3.w;
    }
    #pragma unroll
    for (int o = 0; o < 8; ++o) {
        float ko = KRr[o];
        const float4* kr = (const float4*)(PHtb + o * 16);  // K^T row o
        float4 c0 = kr[0], c1 = kr[1], c2 = kr[2], c3 = kr[3];
        nc[0]+=ko*c0.x; nc[1]+=ko*c0.y; nc[2]+=ko*c0.z; nc[3]+=ko*c0.w;
        nc[4]+=ko*c1.x; nc[5]+=ko*c1.y; nc[6]+=ko*c1.z; nc[7]+=ko*c1.w;
        nc[8]+=ko*c2.x; nc[9]+=ko*c2.y; nc[10]+=ko*c2.z; nc[11]+=ko*c2.w;
        nc[12]+=ko*c3.x; nc[13]+=ko*c3.y; nc[14]+=ko*c3.z; nc[15]+=ko*c3.w;
    }
    __syncthreads();  // all reads of covA / p1T done

    // ---------------- Phase 8: new_cov -> covA ; F^T -> p1T region ----------------
    {
        float4* cd = (float4*)(covA + t * 16);
        cd[0] = make_float4(nc[0], nc[1], nc[2], nc[3]);
        cd[1] = make_float4(nc[4], nc[5], nc[6], nc[7]);
        cd[2] = make_float4(nc[8], nc[9], nc[10], nc[11]);
        cd[3] = make_float4(nc[12], nc[13], nc[14], nc[15]);
    }
    #pragma unroll
    for (int j = 0; j < 16; ++j) p1T[j * 16 + t] = freg[j];  // F^T[j][t] = F[t][j]
    __syncthreads();

    // ---------------- Phase 9: FP = F @ new_cov (row); pred_mean ----------------
    // Issue Q loads early to hide latency under the FP compute.
    const float4* Q4 = (const float4*)(Q + b * 256 + t * 16);
    float4 q0 = Q4[0], q1 = Q4[1], q2 = Q4[2], q3 = Q4[3];

    float fp[16];
    #pragma unroll
    for (int k = 0; k < 16; ++k) fp[k] = 0.0f;
    #pragma unroll
    for (int j = 0; j < 16; ++j) {
        float fj = freg[j];
        const float4* cr = (const float4*)(covA + j * 16);
        float4 c0 = cr[0], c1 = cr[1], c2 = cr[2], c3 = cr[3];
        fp[0]+=fj*c0.x; fp[1]+=fj*c0.y; fp[2]+=fj*c0.z; fp[3]+=fj*c0.w;
        fp[4]+=fj*c1.x; fp[5]+=fj*c1.y; fp[6]+=fj*c1.z; fp[7]+=fj*c1.w;
        fp[8]+=fj*c2.x; fp[9]+=fj*c2.y; fp[10]+=fj*c2.z; fp[11]+=fj*c2.w;
        fp[12]+=fj*c3.x; fp[13]+=fj*c3.y; fp[14]+=fj*c3.z; fp[15]+=fj*c3.w;
    }
    float pm = 0.0f;
    #pragma unroll
    for (int j = 0; j < 16; ++j) pm += freg[j] * nmeanv[j];

    // ---------------- Phase 10: pred_cov row = FP @ F^T + Q ----------------
    float pc[16];
    pc[0]=q0.x; pc[1]=q0.y; pc[2]=q0.z; pc[3]=q0.w;
    pc[4]=q1.x; pc[5]=q1.y; pc[6]=q1.z; pc[7]=q1.w;
    pc[8]=q2.x; pc[9]=q2.y; pc[10]=q2.z; pc[11]=q2.w;
    pc[12]=q3.x; pc[13]=q3.y; pc[14]=q3.z; pc[15]=q3.w;
    #pragma unroll
    for (int k = 0; k < 16; ++k) {
        float fk = fp[k];
        const float4* fr = (const float4*)(p1T + k * 16);  // F^T row k
        float4 c0 = fr[0], c1 = fr[1], c2 = fr[2], c3 = fr[3];
        pc[0]+=fk*c0.x; pc[1]+=fk*c0.y; pc[2]+=fk*c0.z; pc[3]+=fk*c0.w;
        pc[4]+=fk*c1.x; pc[5]+=fk*c1.y; pc[6]+=fk*c1.z; pc[7]+=fk*c1.w;
        pc[8]+=fk*c2.x; pc[9]+=fk*c2.y; pc[10]+=fk*c2.z; pc[11]+=fk*c2.w;
        pc[12]+=fk*c3.x; pc[13]+=fk*c3.y; pc[14]+=fk*c3.z; pc[15]+=fk*c3.w;
    }

    // ---------------- Stores ----------------
    out_mean[b * 16 + t] = pm;
    {
        float4* od = (float4*)(out_cov + b * 256 + t * 16);
        od[0] = make_float4(pc[0], pc[1], pc[2], pc[3]);
        od[1] = make_float4(pc[4], pc[5], pc[6], pc[7]);
        od[2] = make_float4(pc[8], pc[9], pc[10], pc[11]);
        od[3] = make_float4(pc[12], pc[13], pc[14], pc[15]);
    }
}

extern "C" void kernel_launch(void* const* d_in, const int* in_sizes, int n_in,
                              void* d_out, int out_size, void* d_ws, size_t ws_size,
                              hipStream_t stream) {
    const float* input = (const float*)d_in[0];
    const float* mean  = (const float*)d_in[1];
    const float* cov   = (const float*)d_in[2];
    const float* H     = (const float*)d_in[3];
    const float* R     = (const float*)d_in[4];
    const float* F     = (const float*)d_in[5];
    const float* Q     = (const float*)d_in[6];
    float* out = (float*)d_out;
    float* out_mean = out;
    float* out_cov  = out + (size_t)NB * NSTATE;

    dim3 grid(NB / BATCH_PER_BLOCK);
    dim3 block(THREADS);
    hipLaunchKernelGGL(kalman_step_kernel, grid, block, 0, stream,
                       input, mean, cov, H, R, F, Q, out_mean, out_cov);
}